// Round 2
// baseline (343.858 us; speedup 1.0000x reference)
//
#include <hip/hip_runtime.h>
#include <hip/hip_bf16.h>

#define D 128
#define NH 256
#define K1 384
#define BM 64
#define E_TOTAL 320000
#define NNODES 10000

typedef __attribute__((ext_vector_type(8))) short bf16x8;
typedef __attribute__((ext_vector_type(4))) float f32x4;

__device__ __forceinline__ unsigned short f2b(float f) {
  unsigned int u = __builtin_bit_cast(unsigned int, f);
  u += 0x7fffu + ((u >> 16) & 1u);   // round-to-nearest-even
  return (unsigned short)(u >> 16);
}

// nodes fp32 -> bf16 table (makes the per-edge gathers 2B/elem and L2-hot)
__global__ void cast_nodes_kernel(const float* __restrict__ nodes,
                                  ushort* __restrict__ out) {
  int i = (blockIdx.x * 256 + threadIdx.x) * 4;
  float4 v = *(const float4*)(nodes + i);
  ushort4 b;
  b.x = f2b(v.x); b.y = f2b(v.y); b.z = f2b(v.z); b.w = f2b(v.w);
  *(ushort4*)(out + i) = b;
}

// transpose-cast: in fp32 [K][N] -> out bf16 [N][K]
__global__ void transpose_cast_kernel(const float* __restrict__ in,
                                      ushort* __restrict__ out,
                                      int K, int N) {
  __shared__ float tile[64][65];
  int kb = blockIdx.x * 64;
  int nb = blockIdx.y * 64;
  int t = threadIdx.x;     // 256
  int c = t & 63;
  int r0 = t >> 6;
  #pragma unroll
  for (int i = 0; i < 16; ++i) {
    int r = r0 + i * 4;
    tile[r][c] = in[(size_t)(kb + r) * N + nb + c];
  }
  __syncthreads();
  #pragma unroll
  for (int i = 0; i < 16; ++i) {
    int rr = r0 + i * 4;
    out[(size_t)(nb + rr) * K + kb + c] = f2b(tile[c][rr]);
  }
}

// cvec[n] = b1[n] + sum_k globals[k] * W1[384+k][n]
__global__ void cvec_kernel(const float* __restrict__ W1,
                            const float* __restrict__ b1,
                            const float* __restrict__ g,
                            float* __restrict__ cvec) {
  int n = threadIdx.x;  // 256
  float acc = b1[n];
  for (int k = 0; k < D; ++k)
    acc += g[k] * W1[(size_t)(K1 + k) * NH + n];
  cvec[n] = acc;
}

__global__ __launch_bounds__(512, 4) void fused_kernel(
    const float* __restrict__ edges,
    const ushort* __restrict__ nodes_b,
    const int* __restrict__ receivers,
    const int* __restrict__ senders,
    const ushort* __restrict__ W1bT,   // [256][384] bf16
    const float* __restrict__ cvec,    // [256]
    const ushort* __restrict__ W2bT,   // [128][256] bf16
    const float* __restrict__ b2,      // [128]
    float* __restrict__ out) {
  __shared__ char Xs[BM * 768];   // 64 x 384 bf16, byte ^= (row&7)<<4
  __shared__ char Hs[BM * 512];   // 64 x 256 bf16, same swizzle

  const int ebase = blockIdx.x * BM;
  const int tid = threadIdx.x;

  // ---- issue gather indices FIRST (4 per thread) so idx->gather chain overlaps edges
  const int gr0 = tid >> 4;          // 0..31
  const int gr1 = gr0 + 32;          // 32..63
  const int gc = (tid & 15) << 3;    // bf16 col, 8-elem chunks
  int idx_r0 = receivers[ebase + gr0];
  int idx_r1 = receivers[ebase + gr1];
  int idx_s0 = senders[ebase + gr0];
  int idx_s1 = senders[ebase + gr1];

  // ---- edge loads (independent; fill idx latency)
  float4 ev[4];
  int er[4], ec[4];
  #pragma unroll
  for (int it = 0; it < 4; ++it) {
    int ch = tid + it * 512;
    er[it] = ch >> 5;
    ec[it] = (ch & 31) << 2;
    ev[it] = *(const float4*)(edges + (size_t)(ebase + er[it]) * D + ec[it]);
  }

  // ---- gathers (indices resolved by now)
  uint4 gv[4];
  gv[0] = *(const uint4*)(nodes_b + (size_t)idx_r0 * D + gc);
  gv[1] = *(const uint4*)(nodes_b + (size_t)idx_r1 * D + gc);
  gv[2] = *(const uint4*)(nodes_b + (size_t)idx_s0 * D + gc);
  gv[3] = *(const uint4*)(nodes_b + (size_t)idx_s1 * D + gc);

  // ---- convert + LDS writes
  #pragma unroll
  for (int it = 0; it < 4; ++it) {
    ushort4 b;
    b.x = f2b(ev[it].x); b.y = f2b(ev[it].y); b.z = f2b(ev[it].z); b.w = f2b(ev[it].w);
    *(ushort4*)(Xs + er[it] * 768 + ((ec[it] * 2) ^ ((er[it] & 7) << 4))) = b;
  }
  {
    int cR = (D + gc) * 2, cS = (2 * D + gc) * 2;
    *(uint4*)(Xs + gr0 * 768 + (cR ^ ((gr0 & 7) << 4))) = gv[0];
    *(uint4*)(Xs + gr1 * 768 + (cR ^ ((gr1 & 7) << 4))) = gv[1];
    *(uint4*)(Xs + gr0 * 768 + (cS ^ ((gr0 & 7) << 4))) = gv[2];
    *(uint4*)(Xs + gr1 * 768 + (cS ^ ((gr1 & 7) << 4))) = gv[3];
  }
  __syncthreads();

  const int lane = tid & 63;
  const int wave = tid >> 6;
  const int wm = wave >> 2;   // 0..1
  const int wn = wave & 3;    // 0..3
  const int lr = lane & 15;
  const int kg = lane >> 4;   // 0..3

  // hoist epilogue constants (latency overlaps GEMM1)
  float cv[4];
  #pragma unroll
  for (int n = 0; n < 4; ++n) cv[n] = cvec[wn * 64 + n * 16 + lr];
  float bias2[2];
  #pragma unroll
  for (int n = 0; n < 2; ++n) bias2[n] = b2[wn * 32 + n * 16 + lr];

  // ---- GEMM1: [64x384] @ [384x256], double-buffered B prefetch
  const ushort* bptr1[4];
  #pragma unroll
  for (int n = 0; n < 4; ++n)
    bptr1[n] = W1bT + (size_t)(wn * 64 + n * 16 + lr) * K1 + kg * 8;

  f32x4 acc[2][4] = {};
  bf16x8 bbuf[2][4];
  #pragma unroll
  for (int n = 0; n < 4; ++n) bbuf[0][n] = *(const bf16x8*)(bptr1[n]);

  #pragma unroll
  for (int ks = 0; ks < 12; ++ks) {
    if (ks < 11) {
      #pragma unroll
      for (int n = 0; n < 4; ++n)
        bbuf[(ks + 1) & 1][n] = *(const bf16x8*)(bptr1[n] + (ks + 1) * 32);
    }
    bf16x8 a[2];
    const int k0 = ks * 32 + kg * 8;
    #pragma unroll
    for (int m = 0; m < 2; ++m) {
      int row = wm * 32 + m * 16 + lr;
      a[m] = *(const bf16x8*)(Xs + row * 768 + ((k0 * 2) ^ ((row & 7) << 4)));
    }
    #pragma unroll
    for (int m = 0; m < 2; ++m)
      #pragma unroll
      for (int n = 0; n < 4; ++n)
        acc[m][n] = __builtin_amdgcn_mfma_f32_16x16x32_bf16(a[m], bbuf[ks & 1][n], acc[m][n], 0, 0, 0);
  }

  // ---- epilogue 1: + cvec, relu, -> bf16 Hs
  #pragma unroll
  for (int n = 0; n < 4; ++n) {
    int col = wn * 64 + n * 16 + lr;
    #pragma unroll
    for (int m = 0; m < 2; ++m) {
      #pragma unroll
      for (int r = 0; r < 4; ++r) {
        int row = wm * 32 + m * 16 + kg * 4 + r;
        float v = acc[m][n][r] + cv[n];
        v = v > 0.f ? v : 0.f;
        *(ushort*)(Hs + row * 512 + ((col * 2) ^ ((row & 7) << 4))) = f2b(v);
      }
    }
  }
  __syncthreads();

  // ---- GEMM2: [64x256] @ [256x128], double-buffered B prefetch
  const ushort* bptr2[2];
  #pragma unroll
  for (int n = 0; n < 2; ++n)
    bptr2[n] = W2bT + (size_t)(wn * 32 + n * 16 + lr) * NH + kg * 8;

  f32x4 acc2[2][2] = {};
  bf16x8 b2buf[2][2];
  #pragma unroll
  for (int n = 0; n < 2; ++n) b2buf[0][n] = *(const bf16x8*)(bptr2[n]);

  #pragma unroll
  for (int ks = 0; ks < 8; ++ks) {
    if (ks < 7) {
      #pragma unroll
      for (int n = 0; n < 2; ++n)
        b2buf[(ks + 1) & 1][n] = *(const bf16x8*)(bptr2[n] + (ks + 1) * 32);
    }
    bf16x8 a[2];
    const int k0 = ks * 32 + kg * 8;
    #pragma unroll
    for (int m = 0; m < 2; ++m) {
      int row = wm * 32 + m * 16 + lr;
      a[m] = *(const bf16x8*)(Hs + row * 512 + ((k0 * 2) ^ ((row & 7) << 4)));
    }
    #pragma unroll
    for (int m = 0; m < 2; ++m)
      #pragma unroll
      for (int n = 0; n < 2; ++n)
        acc2[m][n] = __builtin_amdgcn_mfma_f32_16x16x32_bf16(a[m], b2buf[ks & 1][n], acc2[m][n], 0, 0, 0);
  }

  // ---- epilogue 2: + b2, store fp32
  #pragma unroll
  for (int n = 0; n < 2; ++n) {
    int col = wn * 32 + n * 16 + lr;
    #pragma unroll
    for (int m = 0; m < 2; ++m) {
      #pragma unroll
      for (int r = 0; r < 4; ++r) {
        int row = wm * 32 + m * 16 + kg * 4 + r;
        out[(size_t)(ebase + row) * D + col] = acc2[m][n][r] + bias2[n];
      }
    }
  }
}

extern "C" void kernel_launch(void* const* d_in, const int* in_sizes, int n_in,
                              void* d_out, int out_size, void* d_ws, size_t ws_size,
                              hipStream_t stream) {
  const float* edges     = (const float*)d_in[0];
  const float* nodes     = (const float*)d_in[1];
  const float* globals_  = (const float*)d_in[2];
  const int*   receivers = (const int*)d_in[3];
  const int*   senders   = (const int*)d_in[4];
  const float* W1        = (const float*)d_in[5];
  const float* b1        = (const float*)d_in[6];
  const float* W2        = (const float*)d_in[7];
  const float* b2        = (const float*)d_in[8];
  float* out = (float*)d_out;

  char* ws = (char*)d_ws;
  ushort* nodes_b = (ushort*)ws;                                // 2,560,000 B
  ushort* W1bT    = (ushort*)(ws + 2560000);                    //   196,608 B
  ushort* W2bT    = (ushort*)(ws + 2560000 + 196608);           //    65,536 B
  float*  cvec    = (float*)(ws + 2560000 + 196608 + 65536);    //     1,024 B

  hipLaunchKernelGGL(cast_nodes_kernel, dim3(NNODES * D / 1024), dim3(256), 0, stream,
                     nodes, nodes_b);
  hipLaunchKernelGGL(transpose_cast_kernel, dim3(K1 / 64, NH / 64), dim3(256), 0, stream,
                     W1, W1bT, K1, NH);
  hipLaunchKernelGGL(transpose_cast_kernel, dim3(NH / 64, D / 64), dim3(256), 0, stream,
                     W2, W2bT, NH, D);
  hipLaunchKernelGGL(cvec_kernel, dim3(1), dim3(256), 0, stream,
                     W1, b1, globals_, cvec);
  hipLaunchKernelGGL(fused_kernel, dim3(E_TOTAL / BM), dim3(512), 0, stream,
                     edges, nodes_b, receivers, senders, W1bT, cvec, W2bT, b2, out);
}

// Round 3
// 144.662 us; speedup vs baseline: 2.3770x; 2.3770x over previous
//
#include <hip/hip_runtime.h>
#include <hip/hip_bf16.h>

#define D 128
#define NH 256
#define K1 384
#define BM 64
#define E_TOTAL 320000
#define NNODES 10000

typedef __attribute__((ext_vector_type(8))) short bf16x8;
typedef __attribute__((ext_vector_type(4))) float f32x4;

__device__ __forceinline__ unsigned short f2b(float f) {
  unsigned int u = __builtin_bit_cast(unsigned int, f);
  u += 0x7fffu + ((u >> 16) & 1u);   // round-to-nearest-even
  return (unsigned short)(u >> 16);
}

// nodes fp32 -> bf16 table
__global__ void cast_nodes_kernel(const float* __restrict__ nodes,
                                  ushort* __restrict__ out) {
  int i = (blockIdx.x * 256 + threadIdx.x) * 4;
  float4 v = *(const float4*)(nodes + i);
  ushort4 b;
  b.x = f2b(v.x); b.y = f2b(v.y); b.z = f2b(v.z); b.w = f2b(v.w);
  *(ushort4*)(out + i) = b;
}

// Pack W1 (fp32 [512][256], rows 0..383 used) into MFMA-fragment order:
// chunk c = nt*12 + ks  (nt: 16-col tile 0..15, ks: K-step 0..11)
// within chunk: lane l (0..63) holds 8 bf16 = W1[ks*32+(l>>4)*8 + j][nt*16+(l&15)]
__global__ void pack_w1_kernel(const float* __restrict__ W1,
                               ushort* __restrict__ W1p) {
  int c = blockIdx.x * 256 + threadIdx.x;   // 12288 threads
  int nt = c / (12 * 64);
  int rem = c % (12 * 64);
  int ks = rem >> 6;
  int l = rem & 63;
  int col = nt * 16 + (l & 15);
  int k0 = ks * 32 + (l >> 4) * 8;
  ushort* dst = W1p + (size_t)c * 8;
  #pragma unroll
  for (int j = 0; j < 8; ++j)
    dst[j] = f2b(W1[(size_t)(k0 + j) * NH + col]);
}

// Pack W2 (fp32 [256][128]) same fragment order: chunk c = nt2*8 + ks
__global__ void pack_w2_kernel(const float* __restrict__ W2,
                               ushort* __restrict__ W2p) {
  int c = blockIdx.x * 256 + threadIdx.x;   // 4096 threads
  int nt2 = c / (8 * 64);
  int rem = c % (8 * 64);
  int ks = rem >> 6;
  int l = rem & 63;
  int col = nt2 * 16 + (l & 15);
  int k0 = ks * 32 + (l >> 4) * 8;
  ushort* dst = W2p + (size_t)c * 8;
  #pragma unroll
  for (int j = 0; j < 8; ++j)
    dst[j] = f2b(W2[(size_t)(k0 + j) * D + col]);
}

// cvec[n] = b1[n] + sum_k globals[k] * W1[384+k][n]
__global__ void cvec_kernel(const float* __restrict__ W1,
                            const float* __restrict__ b1,
                            const float* __restrict__ g,
                            float* __restrict__ cvec) {
  int n = threadIdx.x;  // 256
  float acc = b1[n];
  for (int k = 0; k < D; ++k)
    acc += g[k] * W1[(size_t)(K1 + k) * NH + n];
  cvec[n] = acc;
}

__global__ __launch_bounds__(512, 4) void fused_kernel(
    const float* __restrict__ edges,
    const ushort* __restrict__ nodes_b,
    const int* __restrict__ receivers,
    const int* __restrict__ senders,
    const ushort* __restrict__ W1p,    // packed fragments, 16nt x 12ks x 64lane x 8
    const float* __restrict__ cvec,    // [256]
    const ushort* __restrict__ W2p,    // packed fragments, 8nt x 8ks x 64lane x 8
    const float* __restrict__ b2,      // [128]
    float* __restrict__ out) {
  __shared__ char Xs[BM * 768];   // 64 x 384 bf16, byte ^= (row&7)<<4
  __shared__ char Hs[BM * 512];   // 64 x 256 bf16, same swizzle

  const int ebase = blockIdx.x * BM;
  const int tid = threadIdx.x;

  // ---- gather indices first
  const int gr0 = tid >> 4;
  const int gr1 = gr0 + 32;
  const int gc = (tid & 15) << 3;
  int idx_r0 = receivers[ebase + gr0];
  int idx_r1 = receivers[ebase + gr1];
  int idx_s0 = senders[ebase + gr0];
  int idx_s1 = senders[ebase + gr1];

  // ---- edge loads
  float4 ev[4];
  int er[4], ec[4];
  #pragma unroll
  for (int it = 0; it < 4; ++it) {
    int ch = tid + it * 512;
    er[it] = ch >> 5;
    ec[it] = (ch & 31) << 2;
    ev[it] = *(const float4*)(edges + (size_t)(ebase + er[it]) * D + ec[it]);
  }

  // ---- gathers
  uint4 gv[4];
  gv[0] = *(const uint4*)(nodes_b + (size_t)idx_r0 * D + gc);
  gv[1] = *(const uint4*)(nodes_b + (size_t)idx_r1 * D + gc);
  gv[2] = *(const uint4*)(nodes_b + (size_t)idx_s0 * D + gc);
  gv[3] = *(const uint4*)(nodes_b + (size_t)idx_s1 * D + gc);

  // ---- convert + LDS writes
  #pragma unroll
  for (int it = 0; it < 4; ++it) {
    ushort4 b;
    b.x = f2b(ev[it].x); b.y = f2b(ev[it].y); b.z = f2b(ev[it].z); b.w = f2b(ev[it].w);
    *(ushort4*)(Xs + er[it] * 768 + ((ec[it] * 2) ^ ((er[it] & 7) << 4))) = b;
  }
  {
    int cR = (D + gc) * 2, cS = (2 * D + gc) * 2;
    *(uint4*)(Xs + gr0 * 768 + (cR ^ ((gr0 & 7) << 4))) = gv[0];
    *(uint4*)(Xs + gr1 * 768 + (cR ^ ((gr1 & 7) << 4))) = gv[1];
    *(uint4*)(Xs + gr0 * 768 + (cS ^ ((gr0 & 7) << 4))) = gv[2];
    *(uint4*)(Xs + gr1 * 768 + (cS ^ ((gr1 & 7) << 4))) = gv[3];
  }
  __syncthreads();

  const int lane = tid & 63;
  const int wave = tid >> 6;     // 0..7; owns GEMM1 cols [32w,32w+32), GEMM2 cols [16w,16w+16)
  const int lr = lane & 15;
  const int kg = lane >> 4;

  // epilogue constants
  float cv[2];
  #pragma unroll
  for (int n = 0; n < 2; ++n) cv[n] = cvec[wave * 32 + n * 16 + lr];
  float bias2 = b2[wave * 16 + lr];

  // ---- GEMM1: [64x384] @ [384x32-per-wave], B from packed fragments (coalesced 1KB/instr)
  const ushort* w1base = W1p + (size_t)(wave * 2) * 12 * 512 + lane * 8;

  f32x4 acc[4][2] = {};
  bf16x8 bb[2][2];
  #pragma unroll
  for (int n = 0; n < 2; ++n)
    bb[0][n] = *(const bf16x8*)(w1base + (size_t)n * 12 * 512);

  #pragma unroll
  for (int ks = 0; ks < 12; ++ks) {
    const int cur = ks & 1, nxt = cur ^ 1;
    if (ks < 11) {
      #pragma unroll
      for (int n = 0; n < 2; ++n)
        bb[nxt][n] = *(const bf16x8*)(w1base + (size_t)n * 12 * 512 + (ks + 1) * 512);
    }
    const int k0 = ks * 32 + kg * 8;
    bf16x8 a[4];
    #pragma unroll
    for (int m = 0; m < 4; ++m) {
      int row = m * 16 + lr;
      a[m] = *(const bf16x8*)(Xs + row * 768 + ((k0 * 2) ^ ((row & 7) << 4)));
    }
    #pragma unroll
    for (int m = 0; m < 4; ++m)
      #pragma unroll
      for (int n = 0; n < 2; ++n)
        acc[m][n] = __builtin_amdgcn_mfma_f32_16x16x32_bf16(a[m], bb[cur][n], acc[m][n], 0, 0, 0);
  }

  // ---- epilogue 1: + cvec, relu, -> bf16 Hs (wave writes its 32 cols x all 64 rows)
  #pragma unroll
  for (int n = 0; n < 2; ++n) {
    int col = wave * 32 + n * 16 + lr;
    #pragma unroll
    for (int m = 0; m < 4; ++m) {
      #pragma unroll
      for (int r = 0; r < 4; ++r) {
        int row = m * 16 + kg * 4 + r;
        float v = acc[m][n][r] + cv[n];
        v = v > 0.f ? v : 0.f;
        *(ushort*)(Hs + row * 512 + ((col * 2) ^ ((row & 7) << 4))) = f2b(v);
      }
    }
  }

  // prefetch first W2 fragment before the barrier (no Hs dependency)
  const ushort* w2base = W2p + (size_t)wave * 8 * 512 + lane * 8;
  bf16x8 b2b[2];
  b2b[0] = *(const bf16x8*)(w2base);
  __syncthreads();

  // ---- GEMM2: [64x256] @ [256x16-per-wave]
  f32x4 acc2[4] = {};
  #pragma unroll
  for (int ks = 0; ks < 8; ++ks) {
    const int cur = ks & 1, nxt = cur ^ 1;
    if (ks < 7)
      b2b[nxt] = *(const bf16x8*)(w2base + (ks + 1) * 512);
    const int k0 = ks * 32 + kg * 8;
    bf16x8 a[4];
    #pragma unroll
    for (int m = 0; m < 4; ++m) {
      int row = m * 16 + lr;
      a[m] = *(const bf16x8*)(Hs + row * 512 + ((k0 * 2) ^ ((row & 7) << 4)));
    }
    #pragma unroll
    for (int m = 0; m < 4; ++m)
      acc2[m] = __builtin_amdgcn_mfma_f32_16x16x32_bf16(a[m], b2b[cur], acc2[m], 0, 0, 0);
  }

  // ---- epilogue 2: + b2, store fp32 (wave's 16 cols x 64 rows)
  {
    int col = wave * 16 + lr;
    #pragma unroll
    for (int m = 0; m < 4; ++m) {
      #pragma unroll
      for (int r = 0; r < 4; ++r) {
        int row = m * 16 + kg * 4 + r;
        out[(size_t)(ebase + row) * D + col] = acc2[m][r] + bias2;
      }
    }
  }
}

extern "C" void kernel_launch(void* const* d_in, const int* in_sizes, int n_in,
                              void* d_out, int out_size, void* d_ws, size_t ws_size,
                              hipStream_t stream) {
  const float* edges     = (const float*)d_in[0];
  const float* nodes     = (const float*)d_in[1];
  const float* globals_  = (const float*)d_in[2];
  const int*   receivers = (const int*)d_in[3];
  const int*   senders   = (const int*)d_in[4];
  const float* W1        = (const float*)d_in[5];
  const float* b1        = (const float*)d_in[6];
  const float* W2        = (const float*)d_in[7];
  const float* b2        = (const float*)d_in[8];
  float* out = (float*)d_out;

  char* ws = (char*)d_ws;
  ushort* nodes_b = (ushort*)ws;                                // 2,560,000 B
  ushort* W1p     = (ushort*)(ws + 2560000);                    //   196,608 B
  ushort* W2p     = (ushort*)(ws + 2560000 + 196608);           //    65,536 B
  float*  cvec    = (float*)(ws + 2560000 + 196608 + 65536);    //     1,024 B

  hipLaunchKernelGGL(cast_nodes_kernel, dim3(NNODES * D / 1024), dim3(256), 0, stream,
                     nodes, nodes_b);
  hipLaunchKernelGGL(pack_w1_kernel, dim3(48), dim3(256), 0, stream, W1, W1p);
  hipLaunchKernelGGL(pack_w2_kernel, dim3(16), dim3(256), 0, stream, W2, W2p);
  hipLaunchKernelGGL(cvec_kernel, dim3(1), dim3(256), 0, stream,
                     W1, b1, globals_, cvec);
  hipLaunchKernelGGL(fused_kernel, dim3(E_TOTAL / BM), dim3(512), 0, stream,
                     edges, nodes_b, receivers, senders, W1p, cvec, W2p, b2, out);
}